// Round 3
// baseline (250.749 us; speedup 1.0000x reference)
//
#include <hip/hip_runtime.h>
#include <stdint.h>
#include <math.h>

// Match XLA's default (non-contracted) f32 arithmetic: keeps floor()/compare
// boundaries (bilinear taps, erase box, gridmask) aligned with the reference.
#pragma clang fp contract(off)

struct KeyPair { uint32_t hi, lo; };
struct KTab { KeyPair k[17]; };   // per-param derived keys, see host code

__host__ __device__ __forceinline__ uint32_t rotl32(uint32_t x, int r) {
  return (x << r) | (x >> (32 - r));
}

// JAX threefry2x32: 20 rounds, key injection every 4.
__host__ __device__ __forceinline__ void threefry2x32(uint32_t k0, uint32_t k1,
                                                      uint32_t x0, uint32_t x1,
                                                      uint32_t& o0, uint32_t& o1) {
  const uint32_t ks0 = k0, ks1 = k1, ks2 = k0 ^ k1 ^ 0x1BD11BDAu;
  x0 += ks0; x1 += ks1;
#define TF_R(r) { x0 += x1; x1 = rotl32(x1, (r)); x1 ^= x0; }
  TF_R(13) TF_R(15) TF_R(26) TF_R(6)
  x0 += ks1; x1 += ks2 + 1u;
  TF_R(17) TF_R(29) TF_R(16) TF_R(24)
  x0 += ks2; x1 += ks0 + 2u;
  TF_R(13) TF_R(15) TF_R(26) TF_R(6)
  x0 += ks0; x1 += ks1 + 3u;
  TF_R(17) TF_R(29) TF_R(16) TF_R(24)
  x0 += ks1; x1 += ks2 + 4u;
  TF_R(13) TF_R(15) TF_R(26) TF_R(6)
  x0 += ks2; x1 += ks0 + 5u;
#undef TF_R
  o0 = x0; o1 = x1;
}

// jax_threefry_partitionable=True 32-bit draw: fold both output words.
__host__ __device__ __forceinline__ uint32_t jax_rbits32(KeyPair k, uint32_t i) {
  uint32_t a, b; threefry2x32(k.hi, k.lo, 0u, i, a, b);
  return a ^ b;
}

__host__ __device__ __forceinline__ KeyPair jax_split_child(KeyPair k, uint32_t j) {
  uint32_t a, b; threefry2x32(k.hi, k.lo, 0u, j, a, b);
  KeyPair r; r.hi = a; r.lo = b; return r;
}

__host__ __device__ __forceinline__ float bits_to_unit(uint32_t bits) {
  uint32_t fb = (bits >> 9) | 0x3F800000u;
  return __builtin_bit_cast(float, fb) - 1.0f;   // u in [0,1)
}

__device__ __forceinline__ float map_u(float u, float mn, float mx) {
  return fmaxf(mn, u * (mx - mn) + mn);   // matches jax.random.uniform
}

struct SP {
  float m00, m01, m10, m11, txp, typ;
  float bb, cc, ssat;
  float topv, t2, leftv, l2;
  float dG, lG;
  int flip, doblur, apply_e, apply_g;
};

__global__ __launch_bounds__(512, 6) void aug_kernel(const float* __restrict__ in,
                                                     float* __restrict__ out,
                                                     KTab KT, KeyPair kv, int B) {
  const int b = blockIdx.x;
  const int tid = threadIdx.x;
  __shared__ float simg[3 * 64 * 64];   // 48 KB: one image (input, then warped in place)
  __shared__ float uarr[17];
  __shared__ SP sp;
  __shared__ unsigned long long mgrid, merow, mecol;
  __shared__ float red[8];

  const float* __restrict__ inb = in + (size_t)b * 12288;

  // ---- issue global reads FIRST so HBM latency overlaps the param phase ----
  float4 gA[6];
#pragma unroll
  for (int it = 0; it < 6; ++it)
    gA[it] = *(const float4*)&inb[4 * tid + it * 2048];

  // ---- phase 0a: lane-parallel raw uniform draws ----
  if (tid < 17) {
    KeyPair k = KT.k[tid];
    uint32_t i = (tid == 3) ? 2u * (uint32_t)b
               : (tid == 4) ? 2u * (uint32_t)b + 1u
               : (uint32_t)b;
    uarr[tid] = bits_to_unit(jax_rbits32(k, i));
  }
  __syncthreads();

  // ---- phase 0b: lane 0 maps ranges, trig, writes params ----
  if (tid == 0) {
    const float DEG = 0.017453292519943295f;
    float ang = map_u(uarr[0], -25.f, 25.f) * DEG;
    float shr = map_u(uarr[1], -15.f, 15.f) * DEG;
    float scl = map_u(uarr[2], 0.85f, 1.15f);
    sp.txp = map_u(uarr[3], -0.15f, 0.15f) * 64.f;
    sp.typ = map_u(uarr[4], -0.15f, 0.15f) * 64.f;
    float cA = cosf(ang), sA = sinf(ang), tS = tanf(shr);
    sp.m00 = (cA - tS * (-sA)) / scl;
    sp.m01 = (sA - tS * cA) / scl;
    sp.m10 = (-sA) / scl;
    sp.m11 = cA / scl;
    sp.flip = uarr[5] < 0.6f;
    sp.bb = map_u(uarr[6], 0.7f, 1.3f);
    sp.cc = map_u(uarr[7], 0.7f, 1.3f);
    sp.ssat = map_u(uarr[8], 0.8f, 1.2f);
    sp.doblur = uarr[9] < 0.3f;
    float area = map_u(uarr[10], 0.02f, 0.1f);
    area = area * 64.f;   // mirror reference's (u * H) * W evaluation order
    area = area * 64.f;
    float ratio = map_u(uarr[11], 0.3f, 3.0f);
    float eh = fminf(fmaxf(sqrtf(area * ratio), 1.f), 64.f);
    float ew = fminf(fmaxf(sqrtf(area / ratio), 1.f), 64.f);
    float topv = uarr[12] * (64.f - eh);
    float leftv = uarr[13] * (64.f - ew);
    sp.topv = topv; sp.t2 = topv + eh;
    sp.leftv = leftv; sp.l2 = leftv + ew;
    sp.apply_e = uarr[14] < 0.3f;
    float dG = floorf(map_u(uarr[15], 8.f, 32.f));
    sp.dG = dG;
    sp.lG = floorf(dG * 0.6f);
    sp.apply_g = uarr[16] < 0.3f;
  }
  __syncthreads();

  // ---- phase 0c: 64-bit row/col masks via ballot (H == W == 64, wave 0 only) ----
  if (tid < 64) {
    float rf = (float)tid;
    unsigned long long g = __ballot(fmodf(rf, sp.dG) < sp.lG);       // grid rows==cols
    unsigned long long er = __ballot((rf >= sp.topv) & (rf < sp.t2));
    unsigned long long ec = __ballot((rf >= sp.leftv) & (rf < sp.l2));
    if (tid == 0) { mgrid = g; merow = er; mecol = ec; }
  }

  // ---- stage input image into LDS (coalesced) ----
#pragma unroll
  for (int it = 0; it < 6; ++it)
    *(float4*)&simg[4 * tid + it * 2048] = gA[it];
  __syncthreads();   // staging + mgrid/merow/mecol visible

  // snapshot params into registers
  const float m00 = sp.m00, m01 = sp.m01, m10 = sp.m10, m11 = sp.m11;
  const float txp = sp.txp, typ = sp.typ;
  const float bb = sp.bb, cc = sp.cc, ssat = sp.ssat;
  const int flip = sp.flip, doblur = sp.doblur;
  const int apply_e = sp.apply_e, apply_g = sp.apply_g;
  const unsigned long long mg = mgrid, mer = merow, mec = mecol;

  // ---- phase 1: per-channel in-place affine warp + hflip from LDS ----
  // Thread t handles pixels t, t+512, ... (lane-to-lane w stride = 1 -> tap bank
  // stride ~= m00 ~= 1 -> ~2-way LDS aliasing, free).
  float lsum = 0.f;
  for (int c = 0; c < 3; ++c) {
    float* plane = &simg[c * 4096];
    float vv[8];
#pragma unroll
    for (int it = 0; it < 8; ++it) {
      const int p = tid + it * 512;
      const int h = p >> 6;
      const int w = p & 63;
      const int wsrc = flip ? (63 - w) : w;   // flip(warp(x))[w] == warp-out at 63-w
      const float gx = (float)wsrc - 31.5f;
      const float gy = (float)h - 31.5f;
      const float sx = (m00 * gx + m01 * gy) - txp + 31.5f;
      const float sy = (m10 * gx + m11 * gy) - typ + 31.5f;
      const float fx0 = floorf(sx), fy0 = floorf(sy);
      const float wx = sx - fx0, wy = sy - fy0;
      const int x0 = (int)fx0, y0 = (int)fy0;
      auto tap = [&](int yy, int xx) -> float {
        const bool v = (xx >= 0) & (xx < 64) & (yy >= 0) & (yy < 64);
        const int yc = yy < 0 ? 0 : (yy > 63 ? 63 : yy);
        const int xc = xx < 0 ? 0 : (xx > 63 ? 63 : xx);
        return v ? plane[yc * 64 + xc] : 0.f;
      };
      float v = tap(y0, x0)         * (1.f - wx) * (1.f - wy)
              + tap(y0, x0 + 1)     * wx         * (1.f - wy)
              + tap(y0 + 1, x0)     * (1.f - wx) * wy
              + tap(y0 + 1, x0 + 1) * wx         * wy;
      vv[it] = v;
      lsum += v;
    }
    if (c == 2) {
      // raw-sum reduction (all channels accumulated); red write is to a
      // disjoint LDS region, safe before the read-complete barrier.
      float wsum = lsum;
      for (int off = 32; off > 0; off >>= 1) wsum += __shfl_down(wsum, off);
      if ((tid & 63) == 0) red[tid >> 6] = wsum;
    }
    __syncthreads();   // all reads of plane c complete before overwrite
#pragma unroll
    for (int it = 0; it < 8; ++it) plane[tid + it * 512] = vv[it];
  }
  __syncthreads();   // warped planes + red[] visible

  // ---- color-jitter algebra (blur and pointwise-affine color commute):
  //   x3_c = A*x_c + G*grayx + m'     (A = s*cc*bb, G = (1-s)*cc*bb, m' = mean*(1-cc))
  //   blur(x3)_c = A*bx_c + G*(luma . bx) + m'*blur(1),  blur(1) = edge(h)*edge(w)
  const float mean = (bb * (red[0] + red[1] + red[2] + red[3] +
                            red[4] + red[5] + red[6] + red[7])) / 12288.f;
  const float Ac = ssat * cc * bb;
  const float Gc = (1.f - ssat) * cc * bb;
  const float mprime = mean * (1.f - cc);

  // ---- phase 3: blur (opt) + color + erase + gridmask + clamp + float4 store ----
#pragma unroll 1
  for (int it = 0; it < 2; ++it) {
    const int qq = tid + it * 512;        // quad id 0..1023
    const int h = qq >> 4;
    const int w0 = (qq & 15) * 4;
    float px[3][4];
    if (doblur) {
#pragma unroll
      for (int c = 0; c < 3; ++c) {
        float win[3][6];
#pragma unroll
        for (int r = 0; r < 3; ++r) {
          const int hh = h - 1 + r;
          if (hh >= 0 && hh <= 63) {
            const float* row = &simg[c * 4096 + hh * 64];
            const float4 c4 = *(const float4*)&row[w0];
            win[r][1] = c4.x; win[r][2] = c4.y; win[r][3] = c4.z; win[r][4] = c4.w;
            win[r][0] = (w0 > 0)  ? row[w0 - 1] : 0.f;
            win[r][5] = (w0 < 60) ? row[w0 + 4] : 0.f;
          } else {
            win[r][0] = win[r][1] = win[r][2] = win[r][3] = win[r][4] = win[r][5] = 0.f;
          }
        }
#pragma unroll
        for (int j = 0; j < 4; ++j) {
          const float h0 = 0.25f * win[0][j] + 0.5f * win[0][j + 1] + 0.25f * win[0][j + 2];
          const float h1 = 0.25f * win[1][j] + 0.5f * win[1][j + 1] + 0.25f * win[1][j + 2];
          const float h2 = 0.25f * win[2][j] + 0.5f * win[2][j + 1] + 0.25f * win[2][j + 2];
          px[c][j] = 0.25f * h0 + 0.5f * h1 + 0.25f * h2;
        }
      }
    } else {
#pragma unroll
      for (int c = 0; c < 3; ++c) {
        const float4 c4 = *(const float4*)&simg[c * 4096 + h * 64 + w0];
        px[c][0] = c4.x; px[c][1] = c4.y; px[c][2] = c4.z; px[c][3] = c4.w;
      }
    }
    const float rowe = (h == 0 || h == 63) ? 0.75f : 1.f;
    const bool erow_b = apply_e && ((mer >> h) & 1ull);
    const bool grow_b = apply_g && ((mg >> h) & 1ull);
    float o[3][4];
#pragma unroll
    for (int j = 0; j < 4; ++j) {
      const int w = w0 + j;
      const float gray = 0.299f * px[0][j] + 0.587f * px[1][j] + 0.114f * px[2][j];
      float moff = mprime;
      if (doblur) {
        const float cole = (w == 0 || w == 63) ? 0.75f : 1.f;
        moff = mprime * (rowe * cole);
      }
      const bool do_er = erow_b && ((mec >> w) & 1ull);
      const bool do_gr = grow_b && ((mg >> w) & 1ull);
#pragma unroll
      for (int c = 0; c < 3; ++c) {
        float v = Ac * px[c][j] + Gc * gray + moff;
        if (do_er) {
          const uint32_t idx = ((uint32_t)(b * 3 + c) << 12) | (uint32_t)(h << 6) | (uint32_t)w;
          v = bits_to_unit(jax_rbits32(kv, idx));   // uniform fill [0,1)
        }
        if (do_gr) v = 0.f;
        o[c][j] = fminf(fmaxf(v, 0.f), 1.f);
      }
    }
#pragma unroll
    for (int c = 0; c < 3; ++c) {
      float4 st; st.x = o[c][0]; st.y = o[c][1]; st.z = o[c][2]; st.w = o[c][3];
      *(float4*)&out[(size_t)b * 12288 + c * 4096 + h * 64 + w0] = st;
    }
  }
}

extern "C" void kernel_launch(void* const* d_in, const int* in_sizes, int n_in,
                              void* d_out, int out_size, void* d_ws, size_t ws_size,
                              hipStream_t stream) {
  (void)n_in; (void)out_size; (void)d_ws; (void)ws_size;
  const float* x = (const float*)d_in[0];
  float* out = (float*)d_out;
  const int B = in_sizes[0] / (3 * 64 * 64);
  if (B <= 0) return;

  // Host-side key derivation (pure arithmetic; graph-capture safe).
  KeyPair root; root.hi = 0u; root.lo = 42u;           // jax.random.key(42)
  KeyPair kg = jax_split_child(root, 0);
  KeyPair kf = jax_split_child(root, 1);
  KeyPair kc = jax_split_child(root, 2);
  KeyPair kb = jax_split_child(root, 3);
  KeyPair ke = jax_split_child(root, 4);
  KeyPair km = jax_split_child(root, 5);

  KTab KT;
  KT.k[0]  = jax_split_child(kg, 0);   // angle
  KT.k[1]  = jax_split_child(kg, 1);   // shear
  KT.k[2]  = jax_split_child(kg, 2);   // scale
  KT.k[3]  = jax_split_child(kg, 3);   // translate x (idx 2b)
  KT.k[4]  = KT.k[3];                  // translate y (idx 2b+1)
  KT.k[5]  = kf;                       // hflip
  KT.k[6]  = jax_split_child(kc, 0);   // brightness
  KT.k[7]  = jax_split_child(kc, 1);   // contrast
  KT.k[8]  = jax_split_child(kc, 2);   // saturation
  KT.k[9]  = kb;                       // blur
  KT.k[10] = jax_split_child(ke, 0);   // area
  KT.k[11] = jax_split_child(ke, 1);   // ratio
  KT.k[12] = jax_split_child(ke, 2);   // top
  KT.k[13] = jax_split_child(ke, 3);   // left
  KT.k[14] = jax_split_child(ke, 5);   // apply (erase)
  KT.k[15] = jax_split_child(km, 0);   // grid d
  KT.k[16] = jax_split_child(km, 1);   // apply (grid)
  KeyPair kv = jax_split_child(ke, 4); // erase fill values

  aug_kernel<<<dim3(B), dim3(512), 0, stream>>>(x, out, KT, kv, B);
}

// Round 4
// 184.543 us; speedup vs baseline: 1.3588x; 1.3588x over previous
//
#include <hip/hip_runtime.h>
#include <stdint.h>
#include <math.h>

// Match XLA's default (non-contracted) f32 arithmetic: keeps floor()/compare
// boundaries (bilinear taps, erase box, gridmask) aligned with the reference.
#pragma clang fp contract(off)

struct KeyPair { uint32_t hi, lo; };
struct KTab { KeyPair k[17]; };   // per-param derived keys, see host code

__host__ __device__ __forceinline__ uint32_t rotl32(uint32_t x, int r) {
  return (x << r) | (x >> (32 - r));
}

// JAX threefry2x32: 20 rounds, key injection every 4.
__host__ __device__ __forceinline__ void threefry2x32(uint32_t k0, uint32_t k1,
                                                      uint32_t x0, uint32_t x1,
                                                      uint32_t& o0, uint32_t& o1) {
  const uint32_t ks0 = k0, ks1 = k1, ks2 = k0 ^ k1 ^ 0x1BD11BDAu;
  x0 += ks0; x1 += ks1;
#define TF_R(r) { x0 += x1; x1 = rotl32(x1, (r)); x1 ^= x0; }
  TF_R(13) TF_R(15) TF_R(26) TF_R(6)
  x0 += ks1; x1 += ks2 + 1u;
  TF_R(17) TF_R(29) TF_R(16) TF_R(24)
  x0 += ks2; x1 += ks0 + 2u;
  TF_R(13) TF_R(15) TF_R(26) TF_R(6)
  x0 += ks0; x1 += ks1 + 3u;
  TF_R(17) TF_R(29) TF_R(16) TF_R(24)
  x0 += ks1; x1 += ks2 + 4u;
  TF_R(13) TF_R(15) TF_R(26) TF_R(6)
  x0 += ks2; x1 += ks0 + 5u;
#undef TF_R
  o0 = x0; o1 = x1;
}

// jax_threefry_partitionable=True 32-bit draw: fold both output words.
__host__ __device__ __forceinline__ uint32_t jax_rbits32(KeyPair k, uint32_t i) {
  uint32_t a, b; threefry2x32(k.hi, k.lo, 0u, i, a, b);
  return a ^ b;
}

__host__ __device__ __forceinline__ KeyPair jax_split_child(KeyPair k, uint32_t j) {
  uint32_t a, b; threefry2x32(k.hi, k.lo, 0u, j, a, b);
  KeyPair r; r.hi = a; r.lo = b; return r;
}

__host__ __device__ __forceinline__ float bits_to_unit(uint32_t bits) {
  uint32_t fb = (bits >> 9) | 0x3F800000u;
  return __builtin_bit_cast(float, fb) - 1.0f;   // u in [0,1)
}

__device__ __forceinline__ float map_u(float u, float mn, float mx) {
  return fmaxf(mn, u * (mx - mn) + mn);   // matches jax.random.uniform
}

// Async HBM->LDS, 16 B per lane: lane i lands at ldst + i*16 (wave-uniform base).
__device__ __forceinline__ void gload_lds16(const float* gsrc, float* ldst) {
  __builtin_amdgcn_global_load_lds(
      (const __attribute__((address_space(1))) unsigned int*)gsrc,
      (__attribute__((address_space(3))) unsigned int*)ldst,
      16, 0, 0);
}

struct SP {
  float m00, m01, m10, m11, txp, typ;
  float bb, cc, ssat;
  float topv, t2, leftv, l2;
  float dG, lG;
  int flip, doblur, apply_e, apply_g;
};

__global__ __launch_bounds__(512, 4) void aug_kernel(const float* __restrict__ in,
                                                     float* __restrict__ out,
                                                     KTab KT, KeyPair kv, int B) {
  const int b = blockIdx.x;
  const int tid = threadIdx.x;
  __shared__ float simg[3 * 64 * 64];   // 48 KB: one image (input, then warped in place)
  __shared__ float uarr[17];
  __shared__ SP sp;
  __shared__ unsigned long long mgrid, merow, mecol;
  __shared__ float red[8];

  const float* __restrict__ inb = in + (size_t)b * 12288;

  // ---- stage input HBM->LDS async FIRST (no VGPRs held; overlaps param phase) ----
  {
    const int wv = tid >> 6;            // wave id 0..7
    const int lane = tid & 63;
#pragma unroll
    for (int it = 0; it < 6; ++it) {
      const int base = it * 2048 + wv * 256;     // floats; wave covers 256 floats
      gload_lds16(inb + base + 4 * lane, &simg[base]);
    }
  }

  // ---- phase 0a: lane-parallel raw uniform draws ----
  if (tid < 17) {
    KeyPair k = KT.k[tid];
    uint32_t i = (tid == 3) ? 2u * (uint32_t)b
               : (tid == 4) ? 2u * (uint32_t)b + 1u
               : (uint32_t)b;
    uarr[tid] = bits_to_unit(jax_rbits32(k, i));
  }
  __syncthreads();

  // ---- phase 0b: lane 0 maps ranges, trig, writes params ----
  if (tid == 0) {
    const float DEG = 0.017453292519943295f;
    float ang = map_u(uarr[0], -25.f, 25.f) * DEG;
    float shr = map_u(uarr[1], -15.f, 15.f) * DEG;
    float scl = map_u(uarr[2], 0.85f, 1.15f);
    sp.txp = map_u(uarr[3], -0.15f, 0.15f) * 64.f;
    sp.typ = map_u(uarr[4], -0.15f, 0.15f) * 64.f;
    float cA = cosf(ang), sA = sinf(ang), tS = tanf(shr);
    sp.m00 = (cA - tS * (-sA)) / scl;
    sp.m01 = (sA - tS * cA) / scl;
    sp.m10 = (-sA) / scl;
    sp.m11 = cA / scl;
    sp.flip = uarr[5] < 0.6f;
    sp.bb = map_u(uarr[6], 0.7f, 1.3f);
    sp.cc = map_u(uarr[7], 0.7f, 1.3f);
    sp.ssat = map_u(uarr[8], 0.8f, 1.2f);
    sp.doblur = uarr[9] < 0.3f;
    float area = map_u(uarr[10], 0.02f, 0.1f);
    area = area * 64.f;   // mirror reference's (u * H) * W evaluation order
    area = area * 64.f;
    float ratio = map_u(uarr[11], 0.3f, 3.0f);
    float eh = fminf(fmaxf(sqrtf(area * ratio), 1.f), 64.f);
    float ew = fminf(fmaxf(sqrtf(area / ratio), 1.f), 64.f);
    float topv = uarr[12] * (64.f - eh);
    float leftv = uarr[13] * (64.f - ew);
    sp.topv = topv; sp.t2 = topv + eh;
    sp.leftv = leftv; sp.l2 = leftv + ew;
    sp.apply_e = uarr[14] < 0.3f;
    float dG = floorf(map_u(uarr[15], 8.f, 32.f));
    sp.dG = dG;
    sp.lG = floorf(dG * 0.6f);
    sp.apply_g = uarr[16] < 0.3f;
  }
  __syncthreads();

  // ---- phase 0c: 64-bit row/col masks via ballot (H == W == 64, wave 0 only) ----
  if (tid < 64) {
    float rf = (float)tid;
    unsigned long long g = __ballot(fmodf(rf, sp.dG) < sp.lG);       // grid rows==cols
    unsigned long long er = __ballot((rf >= sp.topv) & (rf < sp.t2));
    unsigned long long ec = __ballot((rf >= sp.leftv) & (rf < sp.l2));
    if (tid == 0) { mgrid = g; merow = er; mecol = ec; }
  }
  __syncthreads();   // masks visible + staging drained (barrier forces vmcnt(0))

  // snapshot params into registers
  const float m00 = sp.m00, m01 = sp.m01, m10 = sp.m10, m11 = sp.m11;
  const float txp = sp.txp, typ = sp.typ;
  const float bb = sp.bb, cc = sp.cc, ssat = sp.ssat;
  const int flip = sp.flip, doblur = sp.doblur;
  const int apply_e = sp.apply_e, apply_g = sp.apply_g;
  const unsigned long long mg = mgrid, mer = merow, mec = mecol;

  // ---- phase 1: per-channel in-place affine warp + hflip from LDS ----
  // Thread t handles pixels t, t+512, ... (lane-to-lane w stride = 1 -> tap bank
  // stride ~= m00 ~= 1 -> ~2-way LDS aliasing, free).
  float lsum = 0.f;
  for (int c = 0; c < 3; ++c) {
    float* plane = &simg[c * 4096];
    float vv[8];
#pragma unroll
    for (int it = 0; it < 8; ++it) {
      const int p = tid + it * 512;
      const int h = p >> 6;
      const int w = p & 63;
      const int wsrc = flip ? (63 - w) : w;   // flip(warp(x))[w] == warp-out at 63-w
      const float gx = (float)wsrc - 31.5f;
      const float gy = (float)h - 31.5f;
      const float sx = (m00 * gx + m01 * gy) - txp + 31.5f;
      const float sy = (m10 * gx + m11 * gy) - typ + 31.5f;
      const float fx0 = floorf(sx), fy0 = floorf(sy);
      const float wx = sx - fx0, wy = sy - fy0;
      const int x0 = (int)fx0, y0 = (int)fy0;
      auto tap = [&](int yy, int xx) -> float {
        const bool v = (xx >= 0) & (xx < 64) & (yy >= 0) & (yy < 64);
        const int yc = yy < 0 ? 0 : (yy > 63 ? 63 : yy);
        const int xc = xx < 0 ? 0 : (xx > 63 ? 63 : xx);
        return v ? plane[yc * 64 + xc] : 0.f;
      };
      float v = tap(y0, x0)         * (1.f - wx) * (1.f - wy)
              + tap(y0, x0 + 1)     * wx         * (1.f - wy)
              + tap(y0 + 1, x0)     * (1.f - wx) * wy
              + tap(y0 + 1, x0 + 1) * wx         * wy;
      vv[it] = v;
      lsum += v;
    }
    if (c == 2) {
      // raw-sum reduction (all channels accumulated); red write is to a
      // disjoint LDS region, safe before the read-complete barrier.
      float wsum = lsum;
      for (int off = 32; off > 0; off >>= 1) wsum += __shfl_down(wsum, off);
      if ((tid & 63) == 0) red[tid >> 6] = wsum;
    }
    __syncthreads();   // all reads of plane c complete before overwrite
#pragma unroll
    for (int it = 0; it < 8; ++it) plane[tid + it * 512] = vv[it];
  }
  __syncthreads();   // warped planes + red[] visible

  // ---- color-jitter algebra (blur and pointwise-affine color commute):
  //   x3_c = A*x_c + G*grayx + m'     (A = s*cc*bb, G = (1-s)*cc*bb, m' = mean*(1-cc))
  //   blur(x3)_c = A*bx_c + G*(luma . bx) + m'*blur(1),  blur(1) = edge(h)*edge(w)
  const float mean = (bb * (red[0] + red[1] + red[2] + red[3] +
                            red[4] + red[5] + red[6] + red[7])) / 12288.f;
  const float Ac = ssat * cc * bb;
  const float Gc = (1.f - ssat) * cc * bb;
  const float mprime = mean * (1.f - cc);

  // ---- phase 3: blur (opt) + color + erase + gridmask + clamp + float4 store ----
#pragma unroll 1
  for (int it = 0; it < 2; ++it) {
    const int qq = tid + it * 512;        // quad id 0..1023
    const int h = qq >> 4;
    const int w0 = (qq & 15) * 4;
    float px[3][4];
    if (doblur) {
#pragma unroll
      for (int c = 0; c < 3; ++c) {
        float win[3][6];
#pragma unroll
        for (int r = 0; r < 3; ++r) {
          const int hh = h - 1 + r;
          if (hh >= 0 && hh <= 63) {
            const float* row = &simg[c * 4096 + hh * 64];
            const float4 c4 = *(const float4*)&row[w0];
            win[r][1] = c4.x; win[r][2] = c4.y; win[r][3] = c4.z; win[r][4] = c4.w;
            win[r][0] = (w0 > 0)  ? row[w0 - 1] : 0.f;
            win[r][5] = (w0 < 60) ? row[w0 + 4] : 0.f;
          } else {
            win[r][0] = win[r][1] = win[r][2] = win[r][3] = win[r][4] = win[r][5] = 0.f;
          }
        }
#pragma unroll
        for (int j = 0; j < 4; ++j) {
          const float h0 = 0.25f * win[0][j] + 0.5f * win[0][j + 1] + 0.25f * win[0][j + 2];
          const float h1 = 0.25f * win[1][j] + 0.5f * win[1][j + 1] + 0.25f * win[1][j + 2];
          const float h2 = 0.25f * win[2][j] + 0.5f * win[2][j + 1] + 0.25f * win[2][j + 2];
          px[c][j] = 0.25f * h0 + 0.5f * h1 + 0.25f * h2;
        }
      }
    } else {
#pragma unroll
      for (int c = 0; c < 3; ++c) {
        const float4 c4 = *(const float4*)&simg[c * 4096 + h * 64 + w0];
        px[c][0] = c4.x; px[c][1] = c4.y; px[c][2] = c4.z; px[c][3] = c4.w;
      }
    }
    const float rowe = (h == 0 || h == 63) ? 0.75f : 1.f;
    const bool erow_b = apply_e && ((mer >> h) & 1ull);
    const bool grow_b = apply_g && ((mg >> h) & 1ull);
    float o[3][4];
#pragma unroll
    for (int j = 0; j < 4; ++j) {
      const int w = w0 + j;
      const float gray = 0.299f * px[0][j] + 0.587f * px[1][j] + 0.114f * px[2][j];
      float moff = mprime;
      if (doblur) {
        const float cole = (w == 0 || w == 63) ? 0.75f : 1.f;
        moff = mprime * (rowe * cole);
      }
      const bool do_er = erow_b && ((mec >> w) & 1ull);
      const bool do_gr = grow_b && ((mg >> w) & 1ull);
#pragma unroll
      for (int c = 0; c < 3; ++c) {
        float v = Ac * px[c][j] + Gc * gray + moff;
        if (do_er) {
          const uint32_t idx = ((uint32_t)(b * 3 + c) << 12) | (uint32_t)(h << 6) | (uint32_t)w;
          v = bits_to_unit(jax_rbits32(kv, idx));   // uniform fill [0,1)
        }
        if (do_gr) v = 0.f;
        o[c][j] = fminf(fmaxf(v, 0.f), 1.f);
      }
    }
#pragma unroll
    for (int c = 0; c < 3; ++c) {
      float4 st; st.x = o[c][0]; st.y = o[c][1]; st.z = o[c][2]; st.w = o[c][3];
      *(float4*)&out[(size_t)b * 12288 + c * 4096 + h * 64 + w0] = st;
    }
  }
}

extern "C" void kernel_launch(void* const* d_in, const int* in_sizes, int n_in,
                              void* d_out, int out_size, void* d_ws, size_t ws_size,
                              hipStream_t stream) {
  (void)n_in; (void)out_size; (void)d_ws; (void)ws_size;
  const float* x = (const float*)d_in[0];
  float* out = (float*)d_out;
  const int B = in_sizes[0] / (3 * 64 * 64);
  if (B <= 0) return;

  // Host-side key derivation (pure arithmetic; graph-capture safe).
  KeyPair root; root.hi = 0u; root.lo = 42u;           // jax.random.key(42)
  KeyPair kg = jax_split_child(root, 0);
  KeyPair kf = jax_split_child(root, 1);
  KeyPair kc = jax_split_child(root, 2);
  KeyPair kb = jax_split_child(root, 3);
  KeyPair ke = jax_split_child(root, 4);
  KeyPair km = jax_split_child(root, 5);

  KTab KT;
  KT.k[0]  = jax_split_child(kg, 0);   // angle
  KT.k[1]  = jax_split_child(kg, 1);   // shear
  KT.k[2]  = jax_split_child(kg, 2);   // scale
  KT.k[3]  = jax_split_child(kg, 3);   // translate x (idx 2b)
  KT.k[4]  = KT.k[3];                  // translate y (idx 2b+1)
  KT.k[5]  = kf;                       // hflip
  KT.k[6]  = jax_split_child(kc, 0);   // brightness
  KT.k[7]  = jax_split_child(kc, 1);   // contrast
  KT.k[8]  = jax_split_child(kc, 2);   // saturation
  KT.k[9]  = kb;                       // blur
  KT.k[10] = jax_split_child(ke, 0);   // area
  KT.k[11] = jax_split_child(ke, 1);   // ratio
  KT.k[12] = jax_split_child(ke, 2);   // top
  KT.k[13] = jax_split_child(ke, 3);   // left
  KT.k[14] = jax_split_child(ke, 5);   // apply (erase)
  KT.k[15] = jax_split_child(km, 0);   // grid d
  KT.k[16] = jax_split_child(km, 1);   // apply (grid)
  KeyPair kv = jax_split_child(ke, 4); // erase fill values

  aug_kernel<<<dim3(B), dim3(512), 0, stream>>>(x, out, KT, kv, B);
}